// Round 10
// baseline (1490.329 us; speedup 1.0000x reference)
//
#include <hip/hip_runtime.h>
#include <hip/hip_fp16.h>
#include <math.h>

// GCN 2-layer. norm_e = dinv[src]*dinv[dst] factorizes: pre-scale at source
// (gemm1 epilogue), aggregate raw, post-scale at destination.
// R9 design: single-pass partition of edges into 391 windows of 256 dst
// nodes (packed pk = src<<8 | dstloc) via LDS FIFOs -> contiguous chunk
// writes (write amp ~1; R8 showed ANY multi-CU 4B scatter amplifies ~13x).
// Aggregation: block per window, LDS acc[256][50]; wave-cooperative
// lane-per-feature processing (R8 failed with thread-per-edge full-row
// gathers + 50 serial LDS atomics; here gathers are coalesced 2-line reads
// and ds_adds are bank-conflict-free). No colidx, no rowptr, no scans.

constexpr int N    = 100000;
constexpr int E    = 3200000;
constexpr int F_IN = 128;
constexpr int H    = 50;
constexpr int HP   = 64;                  // padded h1 row (halves) = 128 B

constexpr int WSH  = 8;                   // window shift: 256 nodes
constexpr int WSZ  = 1 << WSH;
constexpr int NW   = (N + WSZ - 1) / WSZ; // 391 windows
constexpr int CAP  = 24;                  // FIFO capacity per window bin
constexpr int PART_BLK = 256;

constexpr int XS_LD = F_IN + 4;
constexpr int WS_LD = 64;

typedef int int4v __attribute__((ext_vector_type(4)));

// ---------------- build ----------------

__global__ __launch_bounds__(256) void k_zerob(int* __restrict__ bcnt) {
    int i = blockIdx.x * blockDim.x + threadIdx.x;
    if (i < NW) bcnt[i] = 0;
}

// window histogram via LDS
__global__ __launch_bounds__(256) void k_coarse(const int* __restrict__ dst,
                                                int* __restrict__ bcnt) {
    __shared__ int h[NW];
    const int t = threadIdx.x;
    for (int i = t; i < NW; i += 256) h[i] = 0;
    __syncthreads();
    const int4v* dst4 = (const int4v*)dst;
    long q0 = (long)blockIdx.x * (E / 4 / PART_BLK);
    long q1 = q0 + E / 4 / PART_BLK;
    for (long q = q0 + t; q < q1; q += 256) {
        int4v d = __builtin_nontemporal_load(dst4 + q);
        atomicAdd(&h[d.x >> WSH], 1);
        atomicAdd(&h[d.y >> WSH], 1);
        atomicAdd(&h[d.z >> WSH], 1);
        atomicAdd(&h[d.w >> WSH], 1);
    }
    __syncthreads();
    for (int i = t; i < NW; i += 256) atomicAdd(&bcnt[i], h[i]);
}

// parallel exclusive scan of NW window counts (single block, LDS)
__global__ __launch_bounds__(512) void k_scanw(const int* __restrict__ bcnt,
                                               int* __restrict__ bptr,
                                               int* __restrict__ gcur) {
    __shared__ int tmp[512];
    const int t = threadIdx.x;
    int v = (t < NW) ? bcnt[t] : 0;
    tmp[t] = v;
    __syncthreads();
    for (int o = 1; o < 512; o <<= 1) {
        int y = (t >= o) ? tmp[t - o] : 0;
        __syncthreads();
        tmp[t] += y;
        __syncthreads();
    }
    if (t < NW) {
        int excl = tmp[t] - v;
        bptr[t] = excl;
        gcur[t] = excl;
    }
    if (t == NW - 1) bptr[NW] = tmp[t];   // == E
}

// partition edges into window bins; LDS FIFO -> contiguous chunk writes
__global__ __launch_bounds__(256) void k_part(const int* __restrict__ src,
                                              const int* __restrict__ dst,
                                              int* __restrict__ gcur,
                                              int* __restrict__ pairs) {
    __shared__ int fifo[NW][CAP];   // 37.5 KB
    __shared__ int lcnt[NW];
    const int t = threadIdx.x;
    for (int i = t; i < NW; i += 256) lcnt[i] = 0;
    __syncthreads();
    const int4v* dst4 = (const int4v*)dst;
    const int4v* src4 = (const int4v*)src;
    const long Q = E / 4;
    for (long tq = (long)blockIdx.x * 1024; tq < Q; tq += (long)gridDim.x * 1024) {
        #pragma unroll
        for (int u = 0; u < 4; ++u) {
            long q = tq + u * 256 + t;
            if (q < Q) {
                int4v d = __builtin_nontemporal_load(dst4 + q);
                int4v s = __builtin_nontemporal_load(src4 + q);
                #pragma unroll
                for (int e = 0; e < 4; ++e) {
                    int dd = (e == 0) ? d.x : (e == 1) ? d.y : (e == 2) ? d.z : d.w;
                    int ss = (e == 0) ? s.x : (e == 1) ? s.y : (e == 2) ? s.z : s.w;
                    int b  = dd >> WSH;
                    int pk = (ss << WSH) | (dd & (WSZ - 1));
                    int pos = atomicAdd(&lcnt[b], 1);
                    if (pos < CAP) fifo[b][pos] = pk;
                    else { int p = atomicAdd(&gcur[b], 1); pairs[p] = pk; }  // rare
                }
            }
        }
        __syncthreads();
        for (int b = t; b < NW; b += 256) {
            int c = lcnt[b]; if (c > CAP) c = CAP;
            if (c > 0) {
                int base = atomicAdd(&gcur[b], c);
                for (int j = 0; j < c; ++j) pairs[base + j] = fifo[b][j];
                lcnt[b] = 0;
            }
        }
        __syncthreads();
    }
}

// per-window degree: block owns window -> plain coalesced stores
__global__ __launch_bounds__(256) void k_bdeg(const int* __restrict__ pairs,
                                              const int* __restrict__ bptr,
                                              int* __restrict__ degi) {
    __shared__ int cnt[WSZ];
    const int t = threadIdx.x, w = blockIdx.x;
    cnt[t] = 0;
    __syncthreads();
    const int p0 = bptr[w], p1 = bptr[w + 1];
    for (int i = p0 + t; i < p1; i += 256)
        atomicAdd(&cnt[pairs[i] & (WSZ - 1)], 1);
    __syncthreads();
    int node = (w << WSH) + t;
    if (node < N) degi[node] = cnt[t];
}

__global__ __launch_bounds__(256) void k_dinv(const int* __restrict__ degi,
                                              float* __restrict__ dinv) {
    int i = blockIdx.x * blockDim.x + threadIdx.x;
    if (i < N) dinv[i] = rsqrtf((float)degi[i] + 1.0f);   // +1 self loop
}

// ---------------- compute ----------------

// h1[i][j] = dinv[i] * sum_k x[i][k] * W1[k][j], fp16, rows padded to 64
__global__ __launch_bounds__(256, 2) void k_gemm1(const float* __restrict__ x,
                                                  const float* __restrict__ W1,
                                                  const float* __restrict__ dinv,
                                                  __half* __restrict__ h1) {
    __shared__ float xs[64][XS_LD];
    __shared__ float Ws[F_IN][WS_LD];
    const int t = threadIdx.x;
    const int row0 = blockIdx.x * 64;

    for (int i = t; i < F_IN * H; i += 256)
        Ws[i / H][i % H] = W1[i];
    for (int i = t; i < F_IN * (WS_LD - H); i += 256)
        Ws[i / (WS_LD - H)][H + i % (WS_LD - H)] = 0.0f;
    for (int i = t; i < 64 * (F_IN / 4); i += 256) {
        int r  = i >> 5;
        int c4 = i & 31;
        int gr = row0 + r;
        float4 v = make_float4(0.f, 0.f, 0.f, 0.f);
        if (gr < N) v = *(const float4*)(x + (long)gr * F_IN + c4 * 4);
        *(float4*)&xs[r][c4 * 4] = v;
    }
    __syncthreads();

    const int r  = t >> 2;
    const int g  = t & 3;
    const int j0 = g * 16;
    float acc[16];
    #pragma unroll
    for (int u = 0; u < 16; ++u) acc[u] = 0.0f;

    const float* xrow = &xs[r][0];
    #pragma unroll 4
    for (int k0 = 0; k0 < F_IN; k0 += 4) {
        float4 xv = *(const float4*)(xrow + k0);
        float xk[4] = {xv.x, xv.y, xv.z, xv.w};
        #pragma unroll
        for (int kk = 0; kk < 4; ++kk) {
            const float* wrow = &Ws[k0 + kk][j0];
            float4 wa = *(const float4*)(wrow);
            float4 wb = *(const float4*)(wrow + 4);
            float4 wc = *(const float4*)(wrow + 8);
            float4 wd = *(const float4*)(wrow + 12);
            float xr = xk[kk];
            acc[0]  += xr * wa.x; acc[1]  += xr * wa.y;
            acc[2]  += xr * wa.z; acc[3]  += xr * wa.w;
            acc[4]  += xr * wb.x; acc[5]  += xr * wb.y;
            acc[6]  += xr * wb.z; acc[7]  += xr * wb.w;
            acc[8]  += xr * wc.x; acc[9]  += xr * wc.y;
            acc[10] += xr * wc.z; acc[11] += xr * wc.w;
            acc[12] += xr * wd.x; acc[13] += xr * wd.y;
            acc[14] += xr * wd.z; acc[15] += xr * wd.w;
        }
    }

    int gr = row0 + r;
    if (gr >= N) return;
    float di = dinv[gr];
    __half* hrow = h1 + (long)gr * HP + j0;
    #pragma unroll
    for (int u = 0; u < 16; u += 2) {
        int j = j0 + u;
        if (j < H) {
            __half2 hv;
            hv.x = __float2half(di * acc[u]);
            hv.y = (j + 1 < H) ? __float2half(di * acc[u + 1]) : __half(0);
            *(__half2*)(hrow + u) = hv;
        }
    }
}

// layer-1 aggregation: block = 256-node window; wave-cooperative
// lane-per-feature gather + conflict-free ds_add; fused relu+W2 -> h2
__global__ __launch_bounds__(256) void k_agg1_pairs(const int* __restrict__ pairs,
                                                    const int* __restrict__ bptr,
                                                    const __half* __restrict__ h1,
                                                    const float* __restrict__ dinv,
                                                    const float* __restrict__ b1,
                                                    const float* __restrict__ W2,
                                                    float* __restrict__ h2) {
    __shared__ float acc[WSZ * H];   // 51.2 KB
    const int t = threadIdx.x, lane = t & 63, wid = t >> 6;
    const int w = blockIdx.x;
    const bool act = lane < H;

    for (int i = t; i < WSZ * H; i += 256) acc[i] = 0.0f;
    __syncthreads();

    const int p0 = bptr[w], p1 = bptr[w + 1];
    for (int base = p0 + (wid << 6); base < p1; base += 256) {
        const int cnt = min(64, p1 - base);
        int pkl = (lane < cnt) ? pairs[base + lane] : 0;
        if (cnt == 64) {
            #pragma unroll 8
            for (int j = 0; j < 64; ++j) {
                int pk = __shfl(pkl, j);
                if (act) {
                    float v = __half2float(h1[(long)(pk >> WSH) * HP + lane]);
                    atomicAdd(&acc[(pk & (WSZ - 1)) * H + lane], v);
                }
            }
        } else {
            for (int j = 0; j < cnt; ++j) {
                int pk = __shfl(pkl, j);
                if (act) {
                    float v = __half2float(h1[(long)(pk >> WSH) * HP + lane]);
                    atomicAdd(&acc[(pk & (WSZ - 1)) * H + lane], v);
                }
            }
        }
    }
    __syncthreads();

    const float b1v = act ? b1[lane] : 0.0f;
    const float w20 = act ? W2[lane * 2 + 0] : 0.0f;
    const float w21 = act ? W2[lane * 2 + 1] : 0.0f;
    for (int nl = wid; nl < WSZ; nl += 4) {       // wave per node
        long node = (long)w * WSZ + nl;
        if (node >= N) break;
        float di = dinv[node];
        float aval = act ? acc[nl * H + lane] + __half2float(h1[node * HP + lane]) : 0.0f;
        float v = fmaxf(di * aval + b1v, 0.0f);
        float s0 = v * w20, s1 = v * w21;
        #pragma unroll
        for (int o = 32; o > 0; o >>= 1) {
            s0 += __shfl_xor(s0, o);
            s1 += __shfl_xor(s1, o);
        }
        if (lane == 0) {
            h2[node * 2 + 0] = di * s0;
            h2[node * 2 + 1] = di * s1;
        }
    }
}

// layer-2 aggregation + log_softmax: thread-per-pair, 2 KB LDS accumulator
__global__ __launch_bounds__(256) void k_agg2_pairs(const int* __restrict__ pairs,
                                                    const int* __restrict__ bptr,
                                                    const float* __restrict__ h2,
                                                    const float* __restrict__ dinv,
                                                    const float* __restrict__ b2,
                                                    float* __restrict__ out) {
    __shared__ float accA[WSZ * 2];
    const int t = threadIdx.x, w = blockIdx.x;
    accA[t] = 0.0f; accA[t + 256] = 0.0f;
    __syncthreads();

    const int p0 = bptr[w], p1 = bptr[w + 1];
    for (int i = p0 + t; i < p1; i += 256) {
        int pk = pairs[i];
        const float2 hv = *(const float2*)(h2 + (long)(pk >> WSH) * 2);
        int dl = pk & (WSZ - 1);
        atomicAdd(&accA[dl * 2 + 0], hv.x);
        atomicAdd(&accA[dl * 2 + 1], hv.y);
    }
    __syncthreads();

    long node = (long)w * WSZ + t;
    if (node < N) {
        float di = dinv[node];
        float a0 = di * (accA[t * 2 + 0] + h2[node * 2 + 0]) + b2[0];
        float a1 = di * (accA[t * 2 + 1] + h2[node * 2 + 1]) + b2[1];
        float m = fmaxf(a0, a1);
        float lse = m + logf(expf(a0 - m) + expf(a1 - m));
        out[node * 2 + 0] = a0 - lse;
        out[node * 2 + 1] = a1 - lse;
    }
}

extern "C" void kernel_launch(void* const* d_in, const int* in_sizes, int n_in,
                              void* d_out, int out_size, void* d_ws, size_t ws_size,
                              hipStream_t stream) {
    const float* x  = (const float*)d_in[0];
    const int*   ei = (const int*)d_in[1];   // [2][E]: row0 src, row1 dst
    const float* W1 = (const float*)d_in[2];
    const float* b1 = (const float*)d_in[3];
    const float* W2 = (const float*)d_in[4];
    const float* b2 = (const float*)d_in[5];
    float* out = (float*)d_out;

    const int* src = ei;
    const int* dst = ei + E;

    // ws layout
    int*    bcnt = (int*)d_ws;               // NW (392 slots)
    int*    bptr = bcnt + 392;               // NW+1
    int*    gcur = bptr + 392;               // NW
    int*    degi = gcur + 392;               // N
    float*  dinv = (float*)(degi + N);       // N
    int*    pairs = (int*)(dinv + N);        // E
    __half* h1   = (__half*)(pairs + E);     // N*64 halves (12.8 MB)
    float*  h2   = (float*)(h1 + (long)N * HP);  // N*2  (~27 MB total)

    k_zerob<<<2, 256, 0, stream>>>(bcnt);
    k_coarse<<<PART_BLK, 256, 0, stream>>>(dst, bcnt);
    k_scanw<<<1, 512, 0, stream>>>(bcnt, bptr, gcur);
    k_part<<<PART_BLK, 256, 0, stream>>>(src, dst, gcur, pairs);
    k_bdeg<<<NW, 256, 0, stream>>>(pairs, bptr, degi);
    k_dinv<<<(N + 255) / 256, 256, 0, stream>>>(degi, dinv);
    k_gemm1<<<(N + 63) / 64, 256, 0, stream>>>(x, W1, dinv, h1);
    k_agg1_pairs<<<NW, 256, 0, stream>>>(pairs, bptr, h1, dinv, b1, W2, h2);
    k_agg2_pairs<<<NW, 256, 0, stream>>>(pairs, bptr, h2, dinv, b2, out);
}

// Round 11
// 280.713 us; speedup vs baseline: 5.3091x; 5.3091x over previous
//
#include <hip/hip_runtime.h>
#include <hip/hip_fp16.h>
#include <math.h>

// GCN 2-layer. norm_e = dinv[src]*dinv[dst] factorizes: pre-scale at source
// (gemm1 epilogue), aggregate raw, post-scale at destination.
// R10 structure (lessons R2-R9):
//  - k_part: edges -> window-partitioned packed pairs via LDS FIFOs
//    (contiguous chunk writes, amp~1 -- proven R7/R8/R9).
//  - k_csrfill: ONE block per 256-node window builds its CSR slice:
//    LDS histogram -> wave scan -> rowptr/deg/dinv -> scatter-fill colidx
//    confined to the block's own contiguous region => lines live in ONE
//    CU's L2 until full => write amp ~1 (R8's 13x amp was multi-CU
//    interleaved 4B writes in shared lines).
//  - aggregation: CSR wave-per-node (R4-R7 structure, the only gather loop
//    that achieved high MLP: 16K waves, 8 gathers in flight). R8/R9's
//    window-block aggregation starved parallelism (391 blocks -> 16% occ).

constexpr int N    = 100000;
constexpr int E    = 3200000;
constexpr int F_IN = 128;
constexpr int H    = 50;
constexpr int HP   = 64;                  // padded h1 row (halves) = 128 B

constexpr int WSH  = 8;                   // window shift: 256 nodes
constexpr int WSZ  = 1 << WSH;
constexpr int NW   = (N + WSZ - 1) / WSZ; // 391 windows
constexpr int CAP  = 24;                  // FIFO capacity per window bin
constexpr int PART_BLK = 256;

constexpr int XS_LD = F_IN + 4;
constexpr int WS_LD = 64;

typedef int int4v __attribute__((ext_vector_type(4)));

// ---------------- build ----------------

__global__ __launch_bounds__(256) void k_zerob(int* __restrict__ bcnt) {
    int i = blockIdx.x * blockDim.x + threadIdx.x;
    if (i < NW) bcnt[i] = 0;
}

// window histogram via LDS
__global__ __launch_bounds__(256) void k_coarse(const int* __restrict__ dst,
                                                int* __restrict__ bcnt) {
    __shared__ int h[NW];
    const int t = threadIdx.x;
    for (int i = t; i < NW; i += 256) h[i] = 0;
    __syncthreads();
    const int4v* dst4 = (const int4v*)dst;
    long q0 = (long)blockIdx.x * (E / 4 / PART_BLK);
    long q1 = q0 + E / 4 / PART_BLK;
    for (long q = q0 + t; q < q1; q += 256) {
        int4v d = __builtin_nontemporal_load(dst4 + q);
        atomicAdd(&h[d.x >> WSH], 1);
        atomicAdd(&h[d.y >> WSH], 1);
        atomicAdd(&h[d.z >> WSH], 1);
        atomicAdd(&h[d.w >> WSH], 1);
    }
    __syncthreads();
    for (int i = t; i < NW; i += 256) atomicAdd(&bcnt[i], h[i]);
}

// parallel exclusive scan of NW window counts (single block, LDS)
__global__ __launch_bounds__(512) void k_scanw(const int* __restrict__ bcnt,
                                               int* __restrict__ bptr,
                                               int* __restrict__ gcur) {
    __shared__ int tmp[512];
    const int t = threadIdx.x;
    int v = (t < NW) ? bcnt[t] : 0;
    tmp[t] = v;
    __syncthreads();
    for (int o = 1; o < 512; o <<= 1) {
        int y = (t >= o) ? tmp[t - o] : 0;
        __syncthreads();
        tmp[t] += y;
        __syncthreads();
    }
    if (t < NW) {
        int excl = tmp[t] - v;
        bptr[t] = excl;
        gcur[t] = excl;
    }
    if (t == NW - 1) bptr[NW] = tmp[t];   // == E
}

// partition edges into window bins; LDS FIFO -> contiguous chunk writes
__global__ __launch_bounds__(256) void k_part(const int* __restrict__ src,
                                              const int* __restrict__ dst,
                                              int* __restrict__ gcur,
                                              int* __restrict__ pairs) {
    __shared__ int fifo[NW][CAP];   // 37.5 KB
    __shared__ int lcnt[NW];
    const int t = threadIdx.x;
    for (int i = t; i < NW; i += 256) lcnt[i] = 0;
    __syncthreads();
    const int4v* dst4 = (const int4v*)dst;
    const int4v* src4 = (const int4v*)src;
    const long Q = E / 4;
    for (long tq = (long)blockIdx.x * 1024; tq < Q; tq += (long)gridDim.x * 1024) {
        #pragma unroll
        for (int u = 0; u < 4; ++u) {
            long q = tq + u * 256 + t;
            if (q < Q) {
                int4v d = __builtin_nontemporal_load(dst4 + q);
                int4v s = __builtin_nontemporal_load(src4 + q);
                #pragma unroll
                for (int e = 0; e < 4; ++e) {
                    int dd = (e == 0) ? d.x : (e == 1) ? d.y : (e == 2) ? d.z : d.w;
                    int ss = (e == 0) ? s.x : (e == 1) ? s.y : (e == 2) ? s.z : s.w;
                    int b  = dd >> WSH;
                    int pk = (ss << WSH) | (dd & (WSZ - 1));
                    int pos = atomicAdd(&lcnt[b], 1);
                    if (pos < CAP) fifo[b][pos] = pk;
                    else { int p = atomicAdd(&gcur[b], 1); pairs[p] = pk; }  // rare
                }
            }
        }
        __syncthreads();
        for (int b = t; b < NW; b += 256) {
            int c = lcnt[b]; if (c > CAP) c = CAP;
            if (c > 0) {
                int base = atomicAdd(&gcur[b], c);
                for (int j = 0; j < c; ++j) pairs[base + j] = fifo[b][j];
                lcnt[b] = 0;
            }
        }
        __syncthreads();
    }
}

// block per window: histogram -> scan -> rowptr/deg/dinv -> fill colidx.
// Scattered colidx stores stay inside this block's contiguous [p0,p1) region
// (single CU, L2 write-back once per line -> amp ~1).
__global__ __launch_bounds__(256) void k_csrfill(const int* __restrict__ pairs,
                                                 const int* __restrict__ bptr,
                                                 int* __restrict__ colidx,
                                                 int* __restrict__ rowptr,
                                                 int* __restrict__ degn,
                                                 float* __restrict__ dinv) {
    __shared__ int cnt[WSZ];
    __shared__ int cur[WSZ];
    __shared__ int wsum[4];
    const int t = threadIdx.x, w = blockIdx.x;
    const int lane = t & 63, wid = t >> 6;
    cnt[t] = 0;
    __syncthreads();
    const int p0 = bptr[w], p1 = bptr[w + 1];
    for (int i = p0 + t; i < p1; i += 256)
        atomicAdd(&cnt[pairs[i] & (WSZ - 1)], 1);
    __syncthreads();
    int v = cnt[t];
    int incl = v;
    #pragma unroll
    for (int o = 1; o < 64; o <<= 1) {
        int y = __shfl_up(incl, o);
        if (lane >= o) incl += y;
    }
    if (lane == 63) wsum[wid] = incl;
    __syncthreads();
    int wbase = 0;
    #pragma unroll
    for (int u = 0; u < 4; ++u) wbase += (u < wid) ? wsum[u] : 0;
    int excl = wbase + incl - v;
    cur[t] = excl;
    int node = (w << WSH) + t;
    if (node < N) {
        rowptr[node] = p0 + excl;
        degn[node]   = v;
        dinv[node]   = rsqrtf((float)v + 1.0f);   // +1 self loop
    }
    __syncthreads();
    for (int i = p0 + t; i < p1; i += 256) {
        int pk  = pairs[i];
        int pos = atomicAdd(&cur[pk & (WSZ - 1)], 1);
        colidx[p0 + pos] = pk >> WSH;
    }
}

// ---------------- compute ----------------

// h1[i][j] = dinv[i] * sum_k x[i][k] * W1[k][j], fp16, rows padded to 64
__global__ __launch_bounds__(256, 2) void k_gemm1(const float* __restrict__ x,
                                                  const float* __restrict__ W1,
                                                  const float* __restrict__ dinv,
                                                  __half* __restrict__ h1) {
    __shared__ float xs[64][XS_LD];
    __shared__ float Ws[F_IN][WS_LD];
    const int t = threadIdx.x;
    const int row0 = blockIdx.x * 64;

    for (int i = t; i < F_IN * H; i += 256)
        Ws[i / H][i % H] = W1[i];
    for (int i = t; i < F_IN * (WS_LD - H); i += 256)
        Ws[i / (WS_LD - H)][H + i % (WS_LD - H)] = 0.0f;
    for (int i = t; i < 64 * (F_IN / 4); i += 256) {
        int r  = i >> 5;
        int c4 = i & 31;
        int gr = row0 + r;
        float4 v = make_float4(0.f, 0.f, 0.f, 0.f);
        if (gr < N) v = *(const float4*)(x + (long)gr * F_IN + c4 * 4);
        *(float4*)&xs[r][c4 * 4] = v;
    }
    __syncthreads();

    const int r  = t >> 2;
    const int g  = t & 3;
    const int j0 = g * 16;
    float acc[16];
    #pragma unroll
    for (int u = 0; u < 16; ++u) acc[u] = 0.0f;

    const float* xrow = &xs[r][0];
    #pragma unroll 4
    for (int k0 = 0; k0 < F_IN; k0 += 4) {
        float4 xv = *(const float4*)(xrow + k0);
        float xk[4] = {xv.x, xv.y, xv.z, xv.w};
        #pragma unroll
        for (int kk = 0; kk < 4; ++kk) {
            const float* wrow = &Ws[k0 + kk][j0];
            float4 wa = *(const float4*)(wrow);
            float4 wb = *(const float4*)(wrow + 4);
            float4 wc = *(const float4*)(wrow + 8);
            float4 wd = *(const float4*)(wrow + 12);
            float xr = xk[kk];
            acc[0]  += xr * wa.x; acc[1]  += xr * wa.y;
            acc[2]  += xr * wa.z; acc[3]  += xr * wa.w;
            acc[4]  += xr * wb.x; acc[5]  += xr * wb.y;
            acc[6]  += xr * wb.z; acc[7]  += xr * wb.w;
            acc[8]  += xr * wc.x; acc[9]  += xr * wc.y;
            acc[10] += xr * wc.z; acc[11] += xr * wc.w;
            acc[12] += xr * wd.x; acc[13] += xr * wd.y;
            acc[14] += xr * wd.z; acc[15] += xr * wd.w;
        }
    }

    int gr = row0 + r;
    if (gr >= N) return;
    float di = dinv[gr];
    __half* hrow = h1 + (long)gr * HP + j0;
    #pragma unroll
    for (int u = 0; u < 16; u += 2) {
        int j = j0 + u;
        if (j < H) {
            __half2 hv;
            hv.x = __float2half(di * acc[u]);
            hv.y = (j + 1 < H) ? __float2half(di * acc[u + 1]) : __half(0);
            *(__half2*)(hrow + u) = hv;
        }
    }
}

// CSR wave-per-node: agg = self + sum_{nbr} h1[nbr]; z = relu(di*agg+b1);
// h2 = di * (z @ W2).  8 gathers in flight per wave.
__global__ __launch_bounds__(256) void k_agg1_fused(const int* __restrict__ rowptr,
                                                    const int* __restrict__ degn,
                                                    const int* __restrict__ colidx,
                                                    const __half* __restrict__ h1,
                                                    const float* __restrict__ dinv,
                                                    const float* __restrict__ b1,
                                                    const float* __restrict__ W2,
                                                    float* __restrict__ h2) {
    const int lane = threadIdx.x & 63;
    const bool act = lane < H;
    float b1v = act ? b1[lane] : 0.0f;
    float w20 = act ? W2[lane * 2 + 0] : 0.0f;
    float w21 = act ? W2[lane * 2 + 1] : 0.0f;

    long gw = ((long)blockIdx.x * blockDim.x + threadIdx.x) >> 6;
    long nwav = ((long)gridDim.x * blockDim.x) >> 6;
    for (long i = gw; i < N; i += nwav) {
        const int start = rowptr[i];
        const int deg   = degn[i];
        float a0 = act ? __half2float(h1[i * (long)HP + lane]) : 0.0f;  // self
        float a1 = 0.f, a2 = 0.f, a3 = 0.f, a4 = 0.f, a5 = 0.f, a6 = 0.f, a7 = 0.f;
        int k = 0;
        for (; k + 8 <= deg; k += 8) {
            int s0 = colidx[start + k + 0];
            int s1 = colidx[start + k + 1];
            int s2 = colidx[start + k + 2];
            int s3 = colidx[start + k + 3];
            int s4 = colidx[start + k + 4];
            int s5 = colidx[start + k + 5];
            int s6 = colidx[start + k + 6];
            int s7 = colidx[start + k + 7];
            if (act) {
                a0 += __half2float(h1[(long)s0 * HP + lane]);
                a1 += __half2float(h1[(long)s1 * HP + lane]);
                a2 += __half2float(h1[(long)s2 * HP + lane]);
                a3 += __half2float(h1[(long)s3 * HP + lane]);
                a4 += __half2float(h1[(long)s4 * HP + lane]);
                a5 += __half2float(h1[(long)s5 * HP + lane]);
                a6 += __half2float(h1[(long)s6 * HP + lane]);
                a7 += __half2float(h1[(long)s7 * HP + lane]);
            }
        }
        for (; k < deg; ++k) {
            int s = colidx[start + k];
            if (act) a0 += __half2float(h1[(long)s * HP + lane]);
        }
        float agg = ((a0 + a1) + (a2 + a3)) + ((a4 + a5) + (a6 + a7));
        float di = dinv[i];
        float v = fmaxf(di * agg + b1v, 0.0f);
        float p0 = v * w20, p1 = v * w21;
        #pragma unroll
        for (int o = 32; o > 0; o >>= 1) {
            p0 += __shfl_xor(p0, o);
            p1 += __shfl_xor(p1, o);
        }
        if (lane == 0) {
            h2[i * 2 + 0] = di * p0;
            h2[i * 2 + 1] = di * p1;
        }
    }
}

// CSR wave-per-node, lanes over edges: out = log_softmax(di*(sum+self)+b2)
__global__ __launch_bounds__(256) void k_agg2_final(const int* __restrict__ rowptr,
                                                    const int* __restrict__ degn,
                                                    const int* __restrict__ colidx,
                                                    const float* __restrict__ h2,
                                                    const float* __restrict__ dinv,
                                                    const float* __restrict__ b2,
                                                    float* __restrict__ out) {
    const int lane = threadIdx.x & 63;
    long gw = ((long)blockIdx.x * blockDim.x + threadIdx.x) >> 6;
    long nwav = ((long)gridDim.x * blockDim.x) >> 6;
    for (long i = gw; i < N; i += nwav) {
        const int start = rowptr[i];
        const int deg   = degn[i];
        float s0 = 0.0f, s1 = 0.0f;
        for (int k = lane; k < deg; k += 64) {
            int s = colidx[start + k];
            s0 += h2[(long)s * 2 + 0];
            s1 += h2[(long)s * 2 + 1];
        }
        #pragma unroll
        for (int o = 32; o > 0; o >>= 1) {
            s0 += __shfl_xor(s0, o);
            s1 += __shfl_xor(s1, o);
        }
        if (lane == 0) {
            float di = dinv[i];
            float a0 = di * (s0 + h2[i * 2 + 0]) + b2[0];
            float a1 = di * (s1 + h2[i * 2 + 1]) + b2[1];
            float m = fmaxf(a0, a1);
            float lse = m + logf(expf(a0 - m) + expf(a1 - m));
            out[i * 2 + 0] = a0 - lse;
            out[i * 2 + 1] = a1 - lse;
        }
    }
}

extern "C" void kernel_launch(void* const* d_in, const int* in_sizes, int n_in,
                              void* d_out, int out_size, void* d_ws, size_t ws_size,
                              hipStream_t stream) {
    const float* x  = (const float*)d_in[0];
    const int*   ei = (const int*)d_in[1];   // [2][E]: row0 src, row1 dst
    const float* W1 = (const float*)d_in[2];
    const float* b1 = (const float*)d_in[3];
    const float* W2 = (const float*)d_in[4];
    const float* b2 = (const float*)d_in[5];
    float* out = (float*)d_out;

    const int* src = ei;
    const int* dst = ei + E;

    // ws layout
    int*    bcnt   = (int*)d_ws;             // 392
    int*    bptr   = bcnt + 392;             // 393
    int*    gcur   = bptr + 400;             // 392
    int*    rowptr = gcur + 400;             // N
    int*    degn   = rowptr + N;             // N
    float*  dinv   = (float*)(degn + N);     // N
    int*    pairs  = (int*)(dinv + N);       // E
    int*    colidx = pairs + E;              // E
    __half* h1     = (__half*)(colidx + E);  // N*64 halves (12.8 MB)
    float*  h2     = (float*)(h1 + (long)N * HP);  // N*2  (~41 MB total)

    k_zerob<<<2, 256, 0, stream>>>(bcnt);
    k_coarse<<<PART_BLK, 256, 0, stream>>>(dst, bcnt);
    k_scanw<<<1, 512, 0, stream>>>(bcnt, bptr, gcur);
    k_part<<<PART_BLK, 256, 0, stream>>>(src, dst, gcur, pairs);
    k_csrfill<<<NW, 256, 0, stream>>>(pairs, bptr, colidx, rowptr, degn, dinv);
    k_gemm1<<<(N + 63) / 64, 256, 0, stream>>>(x, W1, dinv, h1);
    k_agg1_fused<<<4096, 256, 0, stream>>>(rowptr, degn, colidx, h1, dinv, b1, W2, h2);
    k_agg2_final<<<2048, 256, 0, stream>>>(rowptr, degn, colidx, h2, dinv, b2, out);
}

// Round 12
// 275.879 us; speedup vs baseline: 5.4021x; 1.0175x over previous
//
#include <hip/hip_runtime.h>
#include <hip/hip_fp16.h>
#include <math.h>

// GCN 2-layer. norm_e = dinv[src]*dinv[dst] factorizes: pre-scale at source
// (gemm1 epilogue), aggregate raw, post-scale at destination.
// R10 structure (proven, 280 us): window-partitioned pairs via LDS FIFO
// (chunked writes, amp~1) -> block-local CSR fill (single-CU window region,
// amp~1) -> CSR wave-per-node gather (high MLP).
// R11: agg1 latency-bound (VALUBusy 40%, occ 74%, 2.9 TB/s < ceilings) ->
// 16 gather chains in flight; k_part grid 512; csrfill 512 threads; memset
// replaces k_zerob.

constexpr int N    = 100000;
constexpr int E    = 3200000;
constexpr int F_IN = 128;
constexpr int H    = 50;
constexpr int HP   = 64;                  // padded h1 row (halves) = 128 B

constexpr int WSH  = 8;                   // window shift: 256 nodes
constexpr int WSZ  = 1 << WSH;
constexpr int NW   = (N + WSZ - 1) / WSZ; // 391 windows
constexpr int CAP  = 24;                  // FIFO capacity per window bin
constexpr int PART_BLK = 512;

constexpr int XS_LD = F_IN + 4;
constexpr int WS_LD = 64;

typedef int int4v __attribute__((ext_vector_type(4)));

// ---------------- build ----------------

// window histogram via LDS, grid-stride (safe for any grid)
__global__ __launch_bounds__(256) void k_coarse(const int* __restrict__ dst,
                                                int* __restrict__ bcnt) {
    __shared__ int h[NW];
    const int t = threadIdx.x;
    for (int i = t; i < NW; i += 256) h[i] = 0;
    __syncthreads();
    const int4v* dst4 = (const int4v*)dst;
    const long Q = E / 4;
    for (long q = (long)blockIdx.x * 256 + t; q < Q; q += (long)gridDim.x * 256) {
        int4v d = __builtin_nontemporal_load(dst4 + q);
        atomicAdd(&h[d.x >> WSH], 1);
        atomicAdd(&h[d.y >> WSH], 1);
        atomicAdd(&h[d.z >> WSH], 1);
        atomicAdd(&h[d.w >> WSH], 1);
    }
    __syncthreads();
    for (int i = t; i < NW; i += 256)
        if (h[i]) atomicAdd(&bcnt[i], h[i]);
}

// parallel exclusive scan of NW window counts (single block, LDS)
__global__ __launch_bounds__(512) void k_scanw(const int* __restrict__ bcnt,
                                               int* __restrict__ bptr,
                                               int* __restrict__ gcur) {
    __shared__ int tmp[512];
    const int t = threadIdx.x;
    int v = (t < NW) ? bcnt[t] : 0;
    tmp[t] = v;
    __syncthreads();
    for (int o = 1; o < 512; o <<= 1) {
        int y = (t >= o) ? tmp[t - o] : 0;
        __syncthreads();
        tmp[t] += y;
        __syncthreads();
    }
    if (t < NW) {
        int excl = tmp[t] - v;
        bptr[t] = excl;
        gcur[t] = excl;
    }
    if (t == NW - 1) bptr[NW] = tmp[t];   // == E
}

// partition edges into window bins; LDS FIFO -> contiguous chunk writes
__global__ __launch_bounds__(256) void k_part(const int* __restrict__ src,
                                              const int* __restrict__ dst,
                                              int* __restrict__ gcur,
                                              int* __restrict__ pairs) {
    __shared__ int fifo[NW][CAP];   // 37.5 KB
    __shared__ int lcnt[NW];
    const int t = threadIdx.x;
    for (int i = t; i < NW; i += 256) lcnt[i] = 0;
    __syncthreads();
    const int4v* dst4 = (const int4v*)dst;
    const int4v* src4 = (const int4v*)src;
    const long Q = E / 4;
    for (long tq = (long)blockIdx.x * 1024; tq < Q; tq += (long)gridDim.x * 1024) {
        #pragma unroll
        for (int u = 0; u < 4; ++u) {
            long q = tq + u * 256 + t;
            if (q < Q) {
                int4v d = __builtin_nontemporal_load(dst4 + q);
                int4v s = __builtin_nontemporal_load(src4 + q);
                #pragma unroll
                for (int e = 0; e < 4; ++e) {
                    int dd = (e == 0) ? d.x : (e == 1) ? d.y : (e == 2) ? d.z : d.w;
                    int ss = (e == 0) ? s.x : (e == 1) ? s.y : (e == 2) ? s.z : s.w;
                    int b  = dd >> WSH;
                    int pk = (ss << WSH) | (dd & (WSZ - 1));
                    int pos = atomicAdd(&lcnt[b], 1);
                    if (pos < CAP) fifo[b][pos] = pk;
                    else { int p = atomicAdd(&gcur[b], 1); pairs[p] = pk; }  // rare
                }
            }
        }
        __syncthreads();
        for (int b = t; b < NW; b += 256) {
            int c = lcnt[b]; if (c > CAP) c = CAP;
            if (c > 0) {
                int base = atomicAdd(&gcur[b], c);
                for (int j = 0; j < c; ++j) pairs[base + j] = fifo[b][j];
                lcnt[b] = 0;
            }
        }
        __syncthreads();
    }
}

// block per window: histogram -> scan -> rowptr/deg/dinv -> fill colidx.
// Scattered colidx stores stay inside this block's contiguous [p0,p1) region.
__global__ __launch_bounds__(512) void k_csrfill(const int* __restrict__ pairs,
                                                 const int* __restrict__ bptr,
                                                 int* __restrict__ colidx,
                                                 int* __restrict__ rowptr,
                                                 int* __restrict__ degn,
                                                 float* __restrict__ dinv) {
    __shared__ int cnt[WSZ];
    __shared__ int cur[WSZ];
    __shared__ int wsum[4];
    const int t = threadIdx.x, w = blockIdx.x;
    if (t < WSZ) cnt[t] = 0;
    __syncthreads();
    const int p0 = bptr[w], p1 = bptr[w + 1];
    for (int i = p0 + t; i < p1; i += 512)
        atomicAdd(&cnt[pairs[i] & (WSZ - 1)], 1);
    __syncthreads();
    int v = 0, incl = 0;
    if (t < WSZ) {
        const int lane = t & 63, wid = t >> 6;
        v = cnt[t];
        incl = v;
        #pragma unroll
        for (int o = 1; o < 64; o <<= 1) {
            int y = __shfl_up(incl, o);
            if (lane >= o) incl += y;
        }
        if (lane == 63) wsum[wid] = incl;
    }
    __syncthreads();
    if (t < WSZ) {
        const int wid = t >> 6;
        int wbase = 0;
        #pragma unroll
        for (int u = 0; u < 4; ++u) wbase += (u < wid) ? wsum[u] : 0;
        int excl = wbase + incl - v;
        cur[t] = excl;
        int node = (w << WSH) + t;
        if (node < N) {
            rowptr[node] = p0 + excl;
            degn[node]   = v;
            dinv[node]   = rsqrtf((float)v + 1.0f);   // +1 self loop
        }
    }
    __syncthreads();
    for (int i = p0 + t; i < p1; i += 512) {
        int pk  = pairs[i];
        int pos = atomicAdd(&cur[pk & (WSZ - 1)], 1);
        colidx[p0 + pos] = pk >> WSH;
    }
}

// ---------------- compute ----------------

// h1[i][j] = dinv[i] * sum_k x[i][k] * W1[k][j], fp16, rows padded to 64
__global__ __launch_bounds__(256, 2) void k_gemm1(const float* __restrict__ x,
                                                  const float* __restrict__ W1,
                                                  const float* __restrict__ dinv,
                                                  __half* __restrict__ h1) {
    __shared__ float xs[64][XS_LD];
    __shared__ float Ws[F_IN][WS_LD];
    const int t = threadIdx.x;
    const int row0 = blockIdx.x * 64;

    for (int i = t; i < F_IN * H; i += 256)
        Ws[i / H][i % H] = W1[i];
    for (int i = t; i < F_IN * (WS_LD - H); i += 256)
        Ws[i / (WS_LD - H)][H + i % (WS_LD - H)] = 0.0f;
    for (int i = t; i < 64 * (F_IN / 4); i += 256) {
        int r  = i >> 5;
        int c4 = i & 31;
        int gr = row0 + r;
        float4 v = make_float4(0.f, 0.f, 0.f, 0.f);
        if (gr < N) v = *(const float4*)(x + (long)gr * F_IN + c4 * 4);
        *(float4*)&xs[r][c4 * 4] = v;
    }
    __syncthreads();

    const int r  = t >> 2;
    const int g  = t & 3;
    const int j0 = g * 16;
    float acc[16];
    #pragma unroll
    for (int u = 0; u < 16; ++u) acc[u] = 0.0f;

    const float* xrow = &xs[r][0];
    #pragma unroll 4
    for (int k0 = 0; k0 < F_IN; k0 += 4) {
        float4 xv = *(const float4*)(xrow + k0);
        float xk[4] = {xv.x, xv.y, xv.z, xv.w};
        #pragma unroll
        for (int kk = 0; kk < 4; ++kk) {
            const float* wrow = &Ws[k0 + kk][j0];
            float4 wa = *(const float4*)(wrow);
            float4 wb = *(const float4*)(wrow + 4);
            float4 wc = *(const float4*)(wrow + 8);
            float4 wd = *(const float4*)(wrow + 12);
            float xr = xk[kk];
            acc[0]  += xr * wa.x; acc[1]  += xr * wa.y;
            acc[2]  += xr * wa.z; acc[3]  += xr * wa.w;
            acc[4]  += xr * wb.x; acc[5]  += xr * wb.y;
            acc[6]  += xr * wb.z; acc[7]  += xr * wb.w;
            acc[8]  += xr * wc.x; acc[9]  += xr * wc.y;
            acc[10] += xr * wc.z; acc[11] += xr * wc.w;
            acc[12] += xr * wd.x; acc[13] += xr * wd.y;
            acc[14] += xr * wd.z; acc[15] += xr * wd.w;
        }
    }

    int gr = row0 + r;
    if (gr >= N) return;
    float di = dinv[gr];
    __half* hrow = h1 + (long)gr * HP + j0;
    #pragma unroll
    for (int u = 0; u < 16; u += 2) {
        int j = j0 + u;
        if (j < H) {
            __half2 hv;
            hv.x = __float2half(di * acc[u]);
            hv.y = (j + 1 < H) ? __float2half(di * acc[u + 1]) : __half(0);
            *(__half2*)(hrow + u) = hv;
        }
    }
}

// CSR wave-per-node: agg = self + sum_{nbr} h1[nbr]; z = relu(di*agg+b1);
// h2 = di * (z @ W2).  16 gather chains in flight per wave (R11: MLP x2).
__global__ __launch_bounds__(256) void k_agg1_fused(const int* __restrict__ rowptr,
                                                    const int* __restrict__ degn,
                                                    const int* __restrict__ colidx,
                                                    const __half* __restrict__ h1,
                                                    const float* __restrict__ dinv,
                                                    const float* __restrict__ b1,
                                                    const float* __restrict__ W2,
                                                    float* __restrict__ h2) {
    const int lane = threadIdx.x & 63;
    const bool act = lane < H;
    float b1v = act ? b1[lane] : 0.0f;
    float w20 = act ? W2[lane * 2 + 0] : 0.0f;
    float w21 = act ? W2[lane * 2 + 1] : 0.0f;

    long gw = ((long)blockIdx.x * blockDim.x + threadIdx.x) >> 6;
    long nwav = ((long)gridDim.x * blockDim.x) >> 6;
    for (long i = gw; i < N; i += nwav) {
        const int start = rowptr[i];
        const int deg   = degn[i];
        float a[16];
        a[0] = act ? __half2float(h1[i * (long)HP + lane]) : 0.0f;  // self
        #pragma unroll
        for (int u = 1; u < 16; ++u) a[u] = 0.0f;
        int k = 0;
        for (; k + 16 <= deg; k += 16) {
            int s[16];
            #pragma unroll
            for (int u = 0; u < 16; ++u) s[u] = colidx[start + k + u];
            if (act) {
                #pragma unroll
                for (int u = 0; u < 16; ++u)
                    a[u] += __half2float(h1[(long)s[u] * HP + lane]);
            }
        }
        for (; k + 4 <= deg; k += 4) {
            int s[4];
            #pragma unroll
            for (int u = 0; u < 4; ++u) s[u] = colidx[start + k + u];
            if (act) {
                #pragma unroll
                for (int u = 0; u < 4; ++u)
                    a[u] += __half2float(h1[(long)s[u] * HP + lane]);
            }
        }
        for (; k < deg; ++k) {
            int s = colidx[start + k];
            if (act) a[0] += __half2float(h1[(long)s * HP + lane]);
        }
        float agg = (((a[0] + a[1]) + (a[2] + a[3])) + ((a[4] + a[5]) + (a[6] + a[7])))
                  + (((a[8] + a[9]) + (a[10] + a[11])) + ((a[12] + a[13]) + (a[14] + a[15])));
        float di = dinv[i];
        float v = fmaxf(di * agg + b1v, 0.0f);
        float p0 = v * w20, p1 = v * w21;
        #pragma unroll
        for (int o = 32; o > 0; o >>= 1) {
            p0 += __shfl_xor(p0, o);
            p1 += __shfl_xor(p1, o);
        }
        if (lane == 0) {
            h2[i * 2 + 0] = di * p0;
            h2[i * 2 + 1] = di * p1;
        }
    }
}

// CSR wave-per-node, lanes over edges: out = log_softmax(di*(sum+self)+b2)
__global__ __launch_bounds__(256) void k_agg2_final(const int* __restrict__ rowptr,
                                                    const int* __restrict__ degn,
                                                    const int* __restrict__ colidx,
                                                    const float* __restrict__ h2,
                                                    const float* __restrict__ dinv,
                                                    const float* __restrict__ b2,
                                                    float* __restrict__ out) {
    const int lane = threadIdx.x & 63;
    long gw = ((long)blockIdx.x * blockDim.x + threadIdx.x) >> 6;
    long nwav = ((long)gridDim.x * blockDim.x) >> 6;
    for (long i = gw; i < N; i += nwav) {
        const int start = rowptr[i];
        const int deg   = degn[i];
        float s0 = 0.0f, s1 = 0.0f;
        for (int k = lane; k < deg; k += 64) {
            int s = colidx[start + k];
            s0 += h2[(long)s * 2 + 0];
            s1 += h2[(long)s * 2 + 1];
        }
        #pragma unroll
        for (int o = 32; o > 0; o >>= 1) {
            s0 += __shfl_xor(s0, o);
            s1 += __shfl_xor(s1, o);
        }
        if (lane == 0) {
            float di = dinv[i];
            float a0 = di * (s0 + h2[i * 2 + 0]) + b2[0];
            float a1 = di * (s1 + h2[i * 2 + 1]) + b2[1];
            float m = fmaxf(a0, a1);
            float lse = m + logf(expf(a0 - m) + expf(a1 - m));
            out[i * 2 + 0] = a0 - lse;
            out[i * 2 + 1] = a1 - lse;
        }
    }
}

extern "C" void kernel_launch(void* const* d_in, const int* in_sizes, int n_in,
                              void* d_out, int out_size, void* d_ws, size_t ws_size,
                              hipStream_t stream) {
    const float* x  = (const float*)d_in[0];
    const int*   ei = (const int*)d_in[1];   // [2][E]: row0 src, row1 dst
    const float* W1 = (const float*)d_in[2];
    const float* b1 = (const float*)d_in[3];
    const float* W2 = (const float*)d_in[4];
    const float* b2 = (const float*)d_in[5];
    float* out = (float*)d_out;

    const int* src = ei;
    const int* dst = ei + E;

    // ws layout
    int*    bcnt   = (int*)d_ws;             // 392
    int*    bptr   = bcnt + 392;             // 393
    int*    gcur   = bptr + 400;             // 392
    int*    rowptr = gcur + 400;             // N
    int*    degn   = rowptr + N;             // N
    float*  dinv   = (float*)(degn + N);     // N
    int*    pairs  = (int*)(dinv + N);       // E
    int*    colidx = pairs + E;              // E
    __half* h1     = (__half*)(colidx + E);  // N*64 halves (12.8 MB)
    float*  h2     = (float*)(h1 + (long)N * HP);  // N*2  (~41 MB total)

    hipMemsetAsync(bcnt, 0, 392 * sizeof(int), stream);
    k_coarse<<<PART_BLK, 256, 0, stream>>>(dst, bcnt);
    k_scanw<<<1, 512, 0, stream>>>(bcnt, bptr, gcur);
    k_part<<<PART_BLK, 256, 0, stream>>>(src, dst, gcur, pairs);
    k_csrfill<<<NW, 512, 0, stream>>>(pairs, bptr, colidx, rowptr, degn, dinv);
    k_gemm1<<<(N + 63) / 64, 256, 0, stream>>>(x, W1, dinv, h1);
    k_agg1_fused<<<4096, 256, 0, stream>>>(rowptr, degn, colidx, h1, dinv, b1, W2, h2);
    k_agg2_final<<<2048, 256, 0, stream>>>(rowptr, degn, colidx, h2, dinv, b2, out);
}